// Round 1
// baseline (642.678 us; speedup 1.0000x reference)
//
#include <hip/hip_runtime.h>
#include <cfloat>

#define BB 32
#define AA 8400
#define GG 40
#define NC 80
#define NO 85

// ---------- shared deterministic helpers (noinline => single compiled instance,
// so K2 (assignment) and K4 (multi-resolution argmin) see bitwise-identical costs) ----------

__device__ __attribute__((noinline)) float dev_is_in(float gx, float gy, float xs, float ys, float st)
{
    float xc = (xs + 0.5f) * st;
    float yc = (ys + 0.5f) * st;
    float r  = 1.5f * st;
    float dl = xc - (gx - r);
    float dr = gx + r - xc;
    float dt = yc - (gy - r);
    float db = gy + r - yc;
    float m = fminf(fminf(dl, dr), fminf(dt, db));
    return (m > 0.0f) ? 1.0f : 0.0f;
}

// returns (cost, masked_iou)
__device__ __attribute__((noinline)) float2 dev_cost_iou(
    float gx, float gy, float gw, float gh,
    float px, float py, float pw, float ph,
    float xs, float ys, float st,
    float obj, float clsc, float sl1mp, float fgflag)
{
    float in_flag = dev_is_in(gx, gy, xs, ys, st);
    float tlx = fmaxf(gx - gw * 0.5f, px - pw * 0.5f);
    float tly = fmaxf(gy - gh * 0.5f, py - ph * 0.5f);
    float brx = fminf(gx + gw * 0.5f, px + pw * 0.5f);
    float bry = fminf(gy + gh * 0.5f, py + ph * 0.5f);
    float area_g = gw * gh;
    float area_p = pw * ph;
    float en = (tlx < brx && tly < bry) ? 1.0f : 0.0f;
    float area_i = (brx - tlx) * (bry - tly) * en;
    float iou = area_i / (area_g + area_p - area_i);
    iou = (fgflag != 0.0f) ? iou : 0.0f;
    float iou_cost = -logf(iou + 1e-8f);
    float p = sqrtf(clsc * obj);
    float delta = logf(p) - log1pf(-p);
    float cost = (-sl1mp - delta) + 3.0f * iou_cost + ((in_flag != 0.0f) ? 0.0f : 1000000.0f);
    cost = (fgflag != 0.0f) ? cost : 1000000000.0f;
    return make_float2(cost, iou);
}

__device__ inline float wave_sum(float v)
{
#pragma unroll
    for (int o = 32; o > 0; o >>= 1) v += __shfl_down(v, o, 64);
    return v;
}

// ---------- K1: per-anchor precompute: bbox, obj, sum log1p(-p), fg_anchor ----------
__global__ __launch_bounds__(256) void k1_precompute(
    const float* __restrict__ outputs, const float* __restrict__ labels,
    const float* __restrict__ xs_, const float* __restrict__ ys_, const float* __restrict__ st_,
    float4* __restrict__ rec0, float4* __restrict__ rec1)
{
    int b = blockIdx.y;
    int a = blockIdx.x * blockDim.x + threadIdx.x;
    __shared__ float lgt[GG * 5];
    for (int i = threadIdx.x; i < GG * 5; i += blockDim.x) lgt[i] = labels[b * GG * 5 + i];
    __syncthreads();
    if (a >= AA) return;
    size_t idx = (size_t)b * AA + a;
    const float* o = outputs + idx * NO;
    float px = o[0], py = o[1], pw = o[2], ph = o[3], obj = o[4];
    float s = 0.f;
    for (int c = 0; c < NC; c++) {
        float p = sqrtf(o[5 + c] * obj);
        s += log1pf(-p);
    }
    float xsv = xs_[a], ysv = ys_[a], stv = st_[a];
    float fg = 0.f;
    for (int g = 0; g < GG; g++) {
        if (dev_is_in(lgt[g * 5 + 1], lgt[g * 5 + 2], xsv, ysv, stv) != 0.f) { fg = 1.f; break; }
    }
    rec0[idx] = make_float4(px, py, pw, ph);
    rec1[idx] = make_float4(obj, s, fg, 0.f);
}

// ---------- K2: per-(b,g) SimOTA: top-10 min-cost (stable by (cost,idx)) + top-10 iou ----------
__global__ __launch_bounds__(256) void k2_assign(
    const float* __restrict__ outputs, const float* __restrict__ labels,
    const float* __restrict__ xs_, const float* __restrict__ ys_, const float* __restrict__ st_,
    const float4* __restrict__ rec0, const float4* __restrict__ rec1,
    int* __restrict__ matchcnt, int* __restrict__ matchg)
{
    int g = blockIdx.x, b = blockIdx.y;
    int tid = threadIdx.x;
    const float* L = labels + (b * GG + g) * 5;
    float gcf = L[0], gx = L[1], gy = L[2], gw = L[3], gh = L[4];
    int gc = (int)gcf;

    float tc[10]; int ti[10]; float tv[10];
#pragma unroll
    for (int k = 0; k < 10; k++) { tc[k] = FLT_MAX; ti[k] = 0x7FFFFFFF; tv[k] = 0.f; }

    for (int a = tid; a < AA; a += 256) {
        size_t idx = (size_t)b * AA + a;
        float4 r0 = rec0[idx];
        float4 r1 = rec1[idx];
        float clsc = outputs[idx * NO + 5 + gc];
        float2 ci = dev_cost_iou(gx, gy, gw, gh, r0.x, r0.y, r0.z, r0.w,
                                 xs_[a], ys_[a], st_[a], r1.x, clsc, r1.y, r1.z);
        float c = ci.x, v = ci.y;
        // insert into ascending (cost, idx) top-10 — fully unrolled, register resident
        if (c < tc[9] || (c == tc[9] && a < ti[9])) {
            int p = 0;
#pragma unroll
            for (int k = 0; k < 10; k++) p += ((tc[k] < c) || (tc[k] == c && ti[k] < a)) ? 1 : 0;
#pragma unroll
            for (int k = 9; k >= 1; k--) {
                bool sh = (k > p);
                tc[k] = sh ? tc[k - 1] : tc[k];
                ti[k] = sh ? ti[k - 1] : ti[k];
            }
#pragma unroll
            for (int k = 0; k < 10; k++) if (k == p) { tc[k] = c; ti[k] = a; }
        }
        // insert into descending iou top-10 (values only; sum is all that matters)
        if (v > tv[9]) {
            int p = 0;
#pragma unroll
            for (int k = 0; k < 10; k++) p += (tv[k] > v) ? 1 : 0;
#pragma unroll
            for (int k = 9; k >= 1; k--) { bool sh = (k > p); tv[k] = sh ? tv[k - 1] : tv[k]; }
#pragma unroll
            for (int k = 0; k < 10; k++) if (k == p) tv[k] = v;
        }
    }

    __shared__ float sc[256 * 10];
    __shared__ int   si[256 * 10];
    __shared__ float sv[256 * 10];
#pragma unroll
    for (int k = 0; k < 10; k++) { sc[tid * 10 + k] = tc[k]; si[tid * 10 + k] = ti[k]; sv[tid * 10 + k] = tv[k]; }
    __syncthreads();

    for (int s = 128; s > 0; s >>= 1) {
        if (tid < s) {
            int pa = tid * 10, pb = (tid + s) * 10;
            float mc[10]; int mi[10]; float mv[10];
            int ia = 0, ib = 0;
#pragma unroll
            for (int k = 0; k < 10; k++) {
                bool ta;
                if (ia >= 10) ta = false;
                else if (ib >= 10) ta = true;
                else {
                    float ca = sc[pa + ia], cb = sc[pb + ib];
                    ta = (ca < cb) || (ca == cb && si[pa + ia] < si[pb + ib]);
                }
                if (ta) { mc[k] = sc[pa + ia]; mi[k] = si[pa + ia]; ia++; }
                else    { mc[k] = sc[pb + ib]; mi[k] = si[pb + ib]; ib++; }
            }
            ia = 0; ib = 0;
#pragma unroll
            for (int k = 0; k < 10; k++) {
                bool ta;
                if (ia >= 10) ta = false;
                else if (ib >= 10) ta = true;
                else ta = (sv[pa + ia] >= sv[pb + ib]);
                if (ta) { mv[k] = sv[pa + ia]; ia++; }
                else    { mv[k] = sv[pb + ib]; ib++; }
            }
#pragma unroll
            for (int k = 0; k < 10; k++) { sc[pa + k] = mc[k]; si[pa + k] = mi[k]; sv[pa + k] = mv[k]; }
        }
        __syncthreads();
    }

    if (tid == 0) {
        float sum = 0.f;
#pragma unroll
        for (int k = 0; k < 10; k++) sum += sv[k];
        int dk = (int)sum;              // trunc, matches .astype(int32)
        dk = dk < 1 ? 1 : (dk > 10 ? 10 : dk);
        for (int k = 0; k < dk; k++) {
            int a = si[k];
            atomicAdd(&matchcnt[(size_t)b * AA + a], 1);
            atomicExch(&matchg[(size_t)b * AA + a], g);   // value only used when cnt==1
        }
    }
}

// ---------- K4: resolve multi-match + all loss terms, block-reduce into accumulators ----------
__global__ __launch_bounds__(256) void k4_loss(
    const float* __restrict__ outputs, const float* __restrict__ origin,
    const float* __restrict__ labels,
    const float* __restrict__ xs_, const float* __restrict__ ys_, const float* __restrict__ st_,
    const float4* __restrict__ rec0, const float4* __restrict__ rec1,
    const int* __restrict__ matchcnt, const int* __restrict__ matchg,
    float* __restrict__ acc)
{
    int b = blockIdx.y;
    int a = blockIdx.x * blockDim.x + threadIdx.x;
    __shared__ float lgt[GG * 5];
    for (int i = threadIdx.x; i < GG * 5; i += blockDim.x) lgt[i] = labels[b * GG * 5 + i];
    __syncthreads();

    float t_fg = 0.f, t_iou = 0.f, t_obj = 0.f, t_cls = 0.f, t_l1 = 0.f;
    if (a < AA) {
        size_t idx = (size_t)b * AA + a;
        int cnt = matchcnt[idx];
        float4 r0 = rec0[idx];
        float4 r1 = rec1[idx];
        const float* o = outputs + idx * NO;
        float fg = (cnt > 0) ? 1.f : 0.f;
        // objectness BCE over every anchor
        t_obj = fmaxf(r1.x, 0.f) - r1.x * fg + log1pf(expf(-fabsf(r1.x)));

        if (cnt > 0) {
            float xsv = xs_[a], ysv = ys_[a], stv = st_[a];
            int mg;
            if (cnt == 1) {
                mg = matchg[idx];
            } else {
                // best_gt = argmin over ALL gts (first on tie) — reference semantics
                mg = 0; float best = FLT_MAX;
                for (int g = 0; g < GG; g++) {
                    int gc = (int)lgt[g * 5];
                    float2 ci = dev_cost_iou(lgt[g * 5 + 1], lgt[g * 5 + 2], lgt[g * 5 + 3], lgt[g * 5 + 4],
                                             r0.x, r0.y, r0.z, r0.w, xsv, ysv, stv,
                                             r1.x, o[5 + gc], r1.y, r1.z);
                    if (ci.x < best) { best = ci.x; mg = g; }
                }
            }
            t_fg = 1.f;
            float gx = lgt[mg * 5 + 1], gy = lgt[mg * 5 + 2], gw = lgt[mg * 5 + 3], gh = lgt[mg * 5 + 4];
            int mcls = (int)lgt[mg * 5];
            float2 ci = dev_cost_iou(gx, gy, gw, gh, r0.x, r0.y, r0.z, r0.w,
                                     xsv, ysv, stv, r1.x, o[5 + mcls], r1.y, r1.z);
            float pred_iou = ci.y;   // = ious[matched_gt, a] (masked matrix; matched => fg_anchor)
            // iou_elem(pred=bbox_p, tgt=reg_target) with 1e-16 eps
            float tlx = fmaxf(r0.x - r0.z * 0.5f, gx - gw * 0.5f);
            float tly = fmaxf(r0.y - r0.w * 0.5f, gy - gh * 0.5f);
            float brx = fminf(r0.x + r0.z * 0.5f, gx + gw * 0.5f);
            float bry = fminf(r0.y + r0.w * 0.5f, gy + gh * 0.5f);
            float en = (tlx < brx && tly < bry) ? 1.f : 0.f;
            float ai = (brx - tlx) * (bry - tly) * en;
            float iou = ai / (r0.z * r0.w + gw * gh - ai + 1e-16f);
            t_iou = 1.f - iou * iou;
            // L1
            const float* op = origin + idx * 4;
            float l0 = gx / stv - xsv;
            float l1 = gy / stv - ysv;
            float l2 = logf(gw / stv + 1e-8f);
            float l3 = logf(gh / stv + 1e-8f);
            t_l1 = fabsf(op[0] - l0) + fabsf(op[1] - l1) + fabsf(op[2] - l2) + fabsf(op[3] - l3);
            // class BCE (target = onehot * pred_iou)
            float s = 0.f;
            for (int c = 0; c < NC; c++) {
                float x = o[5 + c];
                float t = (c == mcls) ? pred_iou : 0.f;
                s += fmaxf(x, 0.f) - x * t + log1pf(expf(-fabsf(x)));
            }
            t_cls = s;
        }
    }

    t_fg = wave_sum(t_fg); t_iou = wave_sum(t_iou); t_obj = wave_sum(t_obj);
    t_cls = wave_sum(t_cls); t_l1 = wave_sum(t_l1);
    __shared__ float red[5][4];
    int wv = threadIdx.x >> 6, ln = threadIdx.x & 63;
    if (ln == 0) { red[0][wv] = t_fg; red[1][wv] = t_iou; red[2][wv] = t_obj; red[3][wv] = t_cls; red[4][wv] = t_l1; }
    __syncthreads();
    if (threadIdx.x == 0) {
        atomicAdd(&acc[0], red[0][0] + red[0][1] + red[0][2] + red[0][3]);
        atomicAdd(&acc[1], red[1][0] + red[1][1] + red[1][2] + red[1][3]);
        atomicAdd(&acc[2], red[2][0] + red[2][1] + red[2][2] + red[2][3]);
        atomicAdd(&acc[3], red[3][0] + red[3][1] + red[3][2] + red[3][3]);
        atomicAdd(&acc[4], red[4][0] + red[4][1] + red[4][2] + red[4][3]);
    }
}

// ---------- K5: finalize 6 scalars ----------
__global__ void k5_final(const float* __restrict__ acc, float* __restrict__ out)
{
    if (threadIdx.x == 0 && blockIdx.x == 0) {
        float nfg = fmaxf(acc[0], 1.0f);
        float li = 5.0f * acc[1] / nfg;
        float lo = acc[2] / nfg;
        float lc = acc[3] / nfg;
        float ll = acc[4] / nfg;
        out[0] = li + lo + lc + ll;
        out[1] = li;
        out[2] = lo;
        out[3] = lc;
        out[4] = ll;
        out[5] = nfg / (float)(BB * GG);
    }
}

// ---------- workspace layout ----------
static constexpr size_t NBA      = (size_t)BB * AA;          // 268800
static constexpr size_t OFF_ACC  = NBA * 4;                  // matchcnt: int per anchor
static constexpr size_t OFF_REC0 = OFF_ACC + 32;             // 8 float accumulators
static constexpr size_t OFF_REC1 = OFF_REC0 + NBA * 16;
static constexpr size_t OFF_MG   = OFF_REC1 + NBA * 16;
// total = OFF_MG + NBA*4  ~= 10.8 MB

extern "C" void kernel_launch(void* const* d_in, const int* in_sizes, int n_in,
                              void* d_out, int out_size, void* d_ws, size_t ws_size,
                              hipStream_t stream)
{
    (void)in_sizes; (void)n_in; (void)out_size; (void)ws_size;
    const float* outputs = (const float*)d_in[0];
    const float* origin  = (const float*)d_in[1];
    const float* labels  = (const float*)d_in[2];
    const float* xs_     = (const float*)d_in[3];
    const float* ys_     = (const float*)d_in[4];
    const float* st_     = (const float*)d_in[5];
    float* out = (float*)d_out;
    char* ws = (char*)d_ws;

    int*    matchcnt = (int*)(ws);
    float*  acc      = (float*)(ws + OFF_ACC);
    float4* rec0     = (float4*)(ws + OFF_REC0);
    float4* rec1     = (float4*)(ws + OFF_REC1);
    int*    matchg   = (int*)(ws + OFF_MG);

    hipMemsetAsync(ws, 0, OFF_ACC + 32, stream);   // zero matchcnt + accumulators

    dim3 grid1((AA + 255) / 256, BB);
    k1_precompute<<<grid1, 256, 0, stream>>>(outputs, labels, xs_, ys_, st_, rec0, rec1);

    dim3 grid2(GG, BB);
    k2_assign<<<grid2, 256, 0, stream>>>(outputs, labels, xs_, ys_, st_, rec0, rec1, matchcnt, matchg);

    k4_loss<<<grid1, 256, 0, stream>>>(outputs, origin, labels, xs_, ys_, st_, rec0, rec1, matchcnt, matchg, acc);

    k5_final<<<1, 64, 0, stream>>>(acc, out);
}

// Round 2
// 457.712 us; speedup vs baseline: 1.4041x; 1.4041x over previous
//
#include <hip/hip_runtime.h>
#include <cfloat>

#define BB 32
#define AA 8400
#define GG 40
#define NC 80
#define NO 85

// ---------- deterministic helpers: inline, but all mul/add/sub via _rn intrinsics
// so no FMA contraction => bitwise-identical results at every call site ----------

__device__ inline bool dev_in(float gx, float gy, float xc, float yc, float r)
{
    float dl = __fsub_rn(xc, __fsub_rn(gx, r));
    float dr = __fsub_rn(__fadd_rn(gx, r), xc);
    float dt = __fsub_rn(yc, __fsub_rn(gy, r));
    float db = __fsub_rn(__fadd_rn(gy, r), yc);
    return fminf(fminf(dl, dr), fminf(dt, db)) > 0.0f;
}

// returns (cost, masked_iou); ct = precomputed class-cost term, fg = fg_anchor flag
__device__ inline float2 cost_iou(float gx, float gy, float gw, float gh,
                                  float px, float py, float pw, float ph,
                                  float xc, float yc, float r,
                                  float ct, float fg)
{
    bool in = dev_in(gx, gy, xc, yc, r);
    float gw2 = __fmul_rn(gw, 0.5f), gh2 = __fmul_rn(gh, 0.5f);
    float pw2 = __fmul_rn(pw, 0.5f), ph2 = __fmul_rn(ph, 0.5f);
    float tlx = fmaxf(__fsub_rn(gx, gw2), __fsub_rn(px, pw2));
    float tly = fmaxf(__fsub_rn(gy, gh2), __fsub_rn(py, ph2));
    float brx = fminf(__fadd_rn(gx, gw2), __fadd_rn(px, pw2));
    float bry = fminf(__fadd_rn(gy, gh2), __fadd_rn(py, ph2));
    float en = (tlx < brx && tly < bry) ? 1.0f : 0.0f;
    float ai = __fmul_rn(__fmul_rn(__fsub_rn(brx, tlx), __fsub_rn(bry, tly)), en);
    float ag = __fmul_rn(gw, gh);
    float ap = __fmul_rn(pw, ph);
    float iou = ai / __fsub_rn(__fadd_rn(ag, ap), ai);
    iou = (fg != 0.0f) ? iou : 0.0f;
    float icost = -logf(__fadd_rn(iou, 1e-8f));
    float cost = __fadd_rn(__fadd_rn(ct, __fmul_rn(3.0f, icost)), in ? 0.0f : 1000000.0f);
    cost = (fg != 0.0f) ? cost : 1000000000.0f;
    return make_float2(cost, iou);
}

__device__ inline float wave_sum(float v)
{
#pragma unroll
    for (int o = 32; o > 0; o >>= 1) v += __shfl_down(v, o, 64);
    return v;
}

// ---------- K0: per-anchor geometry (xc, yc, r, st) ----------
__global__ __launch_bounds__(256) void k0_geom(
    const float* __restrict__ xs_, const float* __restrict__ ys_, const float* __restrict__ st_,
    float4* __restrict__ geom)
{
    int a = blockIdx.x * 256 + threadIdx.x;
    if (a < AA) {
        float st = st_[a];
        float xc = __fmul_rn(__fadd_rn(xs_[a], 0.5f), st);
        float yc = __fmul_rn(__fadd_rn(ys_[a], 0.5f), st);
        float r  = __fmul_rn(1.5f, st);
        geom[a] = make_float4(xc, yc, r, st);
    }
}

// ---------- K1: staged coalesced precompute: rec0 (bbox), rec1 (obj, sbce, fg, sl1mp),
//              fgarr, and clsterm[b][g][a] ----------
__global__ __launch_bounds__(256) void k1_precompute(
    const float* __restrict__ outputs, const float* __restrict__ labels,
    const float4* __restrict__ geom,
    float4* __restrict__ rec0, float4* __restrict__ rec1,
    float* __restrict__ fgarr, float* __restrict__ clsterm)
{
    __shared__ __align__(16) float lds[64 * NO];
    __shared__ float lgt[GG * 5];
    __shared__ float2 red[4][64];

    int b = blockIdx.y;
    int a0 = blockIdx.x * 64;
    int tid = threadIdx.x;
    int w = tid >> 6, al = tid & 63;

    for (int i = tid; i < GG * 5; i += 256) lgt[i] = labels[b * GG * 5 + i];
    const float4* src4 = (const float4*)(outputs + ((size_t)b * AA + a0) * NO);
    int nf4 = ((AA - a0) >= 64 ? 64 * NO : (AA - a0) * NO) / 4;
    for (int i = tid; i < nf4; i += 256) ((float4*)lds)[i] = src4[i];
    __syncthreads();

    float obj = lds[al * NO + 4];
    float s1 = 0.0f, s2 = 0.0f;
    int c0 = w * 20;
#pragma unroll 4
    for (int j = 0; j < 20; j++) {
        float x = lds[al * NO + 5 + c0 + j];
        float p = sqrtf(x * obj);
        s1 += log1pf(-p);
        s2 += fmaxf(x, 0.0f) + log1pf(expf(-fabsf(x)));
    }
    red[w][al] = make_float2(s1, s2);
    __syncthreads();

    float sl1mp = red[0][al].x + red[1][al].x + red[2][al].x + red[3][al].x;
    float sbce  = red[0][al].y + red[1][al].y + red[2][al].y + red[3][al].y;

    int a = a0 + al;
    bool valid = a < AA;

    if (w == 0 && valid) {
        float4 gm = geom[a];
        float fg = 0.0f;
        for (int g = 0; g < GG; g++) {
            if (dev_in(lgt[g * 5 + 1], lgt[g * 5 + 2], gm.x, gm.y, gm.z)) { fg = 1.0f; break; }
        }
        size_t idx = (size_t)b * AA + a;
        rec0[idx] = make_float4(lds[al * NO + 0], lds[al * NO + 1], lds[al * NO + 2], lds[al * NO + 3]);
        rec1[idx] = make_float4(obj, sbce, fg, sl1mp);
        fgarr[idx] = fg;
    }

    if (valid) {
        float nsl = -sl1mp;
        for (int gi = 0; gi < 10; gi++) {
            int g = w * 10 + gi;
            int gc = (int)lgt[g * 5];
            float clsv = lds[al * NO + 5 + gc];
            float p = sqrtf(__fmul_rn(clsv, obj));
            float term = __fsub_rn(nsl, __fsub_rn(logf(p), log1pf(-p)));
            clsterm[((size_t)b * GG + g) * AA + a] = term;
        }
    }
}

// ---------- K2: per-(b,g) SimOTA top-10 min-cost + top-10 iou ----------
__global__ __launch_bounds__(256) void k2_assign(
    const float* __restrict__ labels,
    const float4* __restrict__ geom,
    const float4* __restrict__ rec0, const float* __restrict__ fgarr,
    const float* __restrict__ clsterm,
    int* __restrict__ matchcnt, int* __restrict__ matchg)
{
    // XCD-swizzle: all 40 g of one b land on (nominally) the same XCD for L2 reuse
    int lin = blockIdx.x;
    int j = lin >> 3;
    int b = (lin & 7) + 8 * (j / GG);
    int g = j % GG;
    int tid = threadIdx.x;

    const float* L = labels + (b * GG + g) * 5;
    float gx = L[1], gy = L[2], gw = L[3], gh = L[4];

    const float*  ctp = clsterm + ((size_t)b * GG + g) * AA;
    const float4* r0p = rec0 + (size_t)b * AA;
    const float*  fgp = fgarr + (size_t)b * AA;

    float tc[10]; int ti[10]; float tv[10];
#pragma unroll
    for (int k = 0; k < 10; k++) { tc[k] = FLT_MAX; ti[k] = 0x7FFFFFFF; tv[k] = 0.0f; }

    for (int a = tid; a < AA; a += 256) {
        float4 pb = r0p[a];
        float4 gm = geom[a];
        float ct = ctp[a];
        float fgv = fgp[a];
        float2 ci = cost_iou(gx, gy, gw, gh, pb.x, pb.y, pb.z, pb.w, gm.x, gm.y, gm.z, ct, fgv);
        float c = ci.x, v = ci.y;
        if (c < tc[9] || (c == tc[9] && a < ti[9])) {
            int p = 0;
#pragma unroll
            for (int k = 0; k < 10; k++) p += ((tc[k] < c) || (tc[k] == c && ti[k] < a)) ? 1 : 0;
#pragma unroll
            for (int k = 9; k >= 1; k--) {
                bool sh = (k > p);
                tc[k] = sh ? tc[k - 1] : tc[k];
                ti[k] = sh ? ti[k - 1] : ti[k];
            }
#pragma unroll
            for (int k = 0; k < 10; k++) if (k == p) { tc[k] = c; ti[k] = a; }
        }
        if (v > tv[9]) {
            int p = 0;
#pragma unroll
            for (int k = 0; k < 10; k++) p += (tv[k] > v) ? 1 : 0;
#pragma unroll
            for (int k = 9; k >= 1; k--) { bool sh = (k > p); tv[k] = sh ? tv[k - 1] : tv[k]; }
#pragma unroll
            for (int k = 0; k < 10; k++) if (k == p) tv[k] = v;
        }
    }

    __shared__ float sc[256 * 10];
    __shared__ int   si[256 * 10];
    __shared__ float sv[256 * 10];
#pragma unroll
    for (int k = 0; k < 10; k++) { sc[tid * 10 + k] = tc[k]; si[tid * 10 + k] = ti[k]; sv[tid * 10 + k] = tv[k]; }
    __syncthreads();

    for (int s = 128; s > 0; s >>= 1) {
        if (tid < s) {
            int pa = tid * 10, pb2 = (tid + s) * 10;
            float mc[10]; int mi[10]; float mv[10];
            int ia = 0, ib = 0;
#pragma unroll
            for (int k = 0; k < 10; k++) {
                bool ta;
                if (ia >= 10) ta = false;
                else if (ib >= 10) ta = true;
                else {
                    float ca = sc[pa + ia], cb = sc[pb2 + ib];
                    ta = (ca < cb) || (ca == cb && si[pa + ia] < si[pb2 + ib]);
                }
                if (ta) { mc[k] = sc[pa + ia]; mi[k] = si[pa + ia]; ia++; }
                else    { mc[k] = sc[pb2 + ib]; mi[k] = si[pb2 + ib]; ib++; }
            }
            ia = 0; ib = 0;
#pragma unroll
            for (int k = 0; k < 10; k++) {
                bool ta;
                if (ia >= 10) ta = false;
                else if (ib >= 10) ta = true;
                else ta = (sv[pa + ia] >= sv[pb2 + ib]);
                if (ta) { mv[k] = sv[pa + ia]; ia++; }
                else    { mv[k] = sv[pb2 + ib]; ib++; }
            }
#pragma unroll
            for (int k = 0; k < 10; k++) { sc[pa + k] = mc[k]; si[pa + k] = mi[k]; sv[pa + k] = mv[k]; }
        }
        __syncthreads();
    }

    if (tid == 0) {
        float sum = 0.0f;
#pragma unroll
        for (int k = 0; k < 10; k++) sum += sv[k];
        int dk = (int)sum;
        dk = dk < 1 ? 1 : (dk > 10 ? 10 : dk);
        for (int k = 0; k < dk; k++) {
            int a = si[k];
            atomicAdd(&matchcnt[(size_t)b * AA + a], 1);
            atomicExch(&matchg[(size_t)b * AA + a], g);
        }
    }
}

// ---------- K4: resolve multi-match + all loss terms ----------
__global__ __launch_bounds__(256) void k4_loss(
    const float* __restrict__ outputs, const float* __restrict__ origin,
    const float* __restrict__ labels,
    const float* __restrict__ xs_, const float* __restrict__ ys_, const float* __restrict__ st_,
    const float4* __restrict__ geom,
    const float4* __restrict__ rec0, const float4* __restrict__ rec1,
    const float* __restrict__ clsterm,
    const int* __restrict__ matchcnt, const int* __restrict__ matchg,
    float* __restrict__ acc)
{
    int b = blockIdx.y;
    int a = blockIdx.x * blockDim.x + threadIdx.x;
    __shared__ float lgt[GG * 5];
    for (int i = threadIdx.x; i < GG * 5; i += blockDim.x) lgt[i] = labels[b * GG * 5 + i];
    __syncthreads();

    float t_fg = 0.0f, t_iou = 0.0f, t_obj = 0.0f, t_cls = 0.0f, t_l1 = 0.0f;
    if (a < AA) {
        size_t idx = (size_t)b * AA + a;
        int cnt = matchcnt[idx];
        float4 r1 = rec1[idx];
        float fg = (cnt > 0) ? 1.0f : 0.0f;
        t_obj = fmaxf(r1.x, 0.0f) - r1.x * fg + log1pf(expf(-fabsf(r1.x)));

        if (cnt > 0) {
            float4 pb = rec0[idx];
            float4 gm = geom[a];
            int mg;
            if (cnt == 1) {
                mg = matchg[idx];
            } else {
                mg = 0; float best = FLT_MAX;
                for (int g = 0; g < GG; g++) {
                    float ct = clsterm[((size_t)b * GG + g) * AA + a];
                    float2 ci = cost_iou(lgt[g * 5 + 1], lgt[g * 5 + 2], lgt[g * 5 + 3], lgt[g * 5 + 4],
                                         pb.x, pb.y, pb.z, pb.w, gm.x, gm.y, gm.z, ct, 1.0f);
                    if (ci.x < best) { best = ci.x; mg = g; }
                }
            }
            t_fg = 1.0f;
            float gx = lgt[mg * 5 + 1], gy = lgt[mg * 5 + 2], gw = lgt[mg * 5 + 3], gh = lgt[mg * 5 + 4];
            int mcls = (int)lgt[mg * 5];
            float ctm = clsterm[((size_t)b * GG + mg) * AA + a];
            float2 ci = cost_iou(gx, gy, gw, gh, pb.x, pb.y, pb.z, pb.w, gm.x, gm.y, gm.z, ctm, 1.0f);
            float pred_iou = ci.y;
            // iou_elem with 1e-16 eps (loss value path — plain fp ok)
            float tlx = fmaxf(pb.x - pb.z * 0.5f, gx - gw * 0.5f);
            float tly = fmaxf(pb.y - pb.w * 0.5f, gy - gh * 0.5f);
            float brx = fminf(pb.x + pb.z * 0.5f, gx + gw * 0.5f);
            float bry = fminf(pb.y + pb.w * 0.5f, gy + gh * 0.5f);
            float en = (tlx < brx && tly < bry) ? 1.0f : 0.0f;
            float ai = (brx - tlx) * (bry - tly) * en;
            float iou = ai / (pb.z * pb.w + gw * gh - ai + 1e-16f);
            t_iou = 1.0f - iou * iou;
            const float* op = origin + idx * 4;
            float stv = st_[a], xsv = xs_[a], ysv = ys_[a];
            float l0 = gx / stv - xsv;
            float l1 = gy / stv - ysv;
            float l2 = logf(gw / stv + 1e-8f);
            float l3 = logf(gh / stv + 1e-8f);
            t_l1 = fabsf(op[0] - l0) + fabsf(op[1] - l1) + fabsf(op[2] - l2) + fabsf(op[3] - l3);
            float clsc = outputs[idx * NO + 5 + mcls];
            t_cls = r1.y - clsc * pred_iou;   // sbce - x_mcls * pred_iou
        }
    }

    t_fg = wave_sum(t_fg); t_iou = wave_sum(t_iou); t_obj = wave_sum(t_obj);
    t_cls = wave_sum(t_cls); t_l1 = wave_sum(t_l1);
    __shared__ float red[5][4];
    int wv = threadIdx.x >> 6, ln = threadIdx.x & 63;
    if (ln == 0) { red[0][wv] = t_fg; red[1][wv] = t_iou; red[2][wv] = t_obj; red[3][wv] = t_cls; red[4][wv] = t_l1; }
    __syncthreads();
    if (threadIdx.x == 0) {
        atomicAdd(&acc[0], red[0][0] + red[0][1] + red[0][2] + red[0][3]);
        atomicAdd(&acc[1], red[1][0] + red[1][1] + red[1][2] + red[1][3]);
        atomicAdd(&acc[2], red[2][0] + red[2][1] + red[2][2] + red[2][3]);
        atomicAdd(&acc[3], red[3][0] + red[3][1] + red[3][2] + red[3][3]);
        atomicAdd(&acc[4], red[4][0] + red[4][1] + red[4][2] + red[4][3]);
    }
}

// ---------- K5: finalize ----------
__global__ void k5_final(const float* __restrict__ acc, float* __restrict__ out)
{
    if (threadIdx.x == 0 && blockIdx.x == 0) {
        float nfg = fmaxf(acc[0], 1.0f);
        float li = 5.0f * acc[1] / nfg;
        float lo = acc[2] / nfg;
        float lc = acc[3] / nfg;
        float ll = acc[4] / nfg;
        out[0] = li + lo + lc + ll;
        out[1] = li;
        out[2] = lo;
        out[3] = lc;
        out[4] = ll;
        out[5] = nfg / (float)(BB * GG);
    }
}

// ---------- workspace layout ----------
static constexpr size_t NBA      = (size_t)BB * AA;            // 268800
static constexpr size_t OFF_ACC  = NBA * 4;                    // matchcnt
static constexpr size_t OFF_REC0 = OFF_ACC + 32;               // 16B-aligned
static constexpr size_t OFF_REC1 = OFF_REC0 + NBA * 16;
static constexpr size_t OFF_MG   = OFF_REC1 + NBA * 16;
static constexpr size_t OFF_FG   = OFF_MG + NBA * 4;
static constexpr size_t OFF_GEOM = OFF_FG + NBA * 4;
static constexpr size_t OFF_CT   = OFF_GEOM + (size_t)AA * 16;
// total = OFF_CT + BB*GG*AA*4  ~= 55 MB

extern "C" void kernel_launch(void* const* d_in, const int* in_sizes, int n_in,
                              void* d_out, int out_size, void* d_ws, size_t ws_size,
                              hipStream_t stream)
{
    (void)in_sizes; (void)n_in; (void)out_size; (void)ws_size;
    const float* outputs = (const float*)d_in[0];
    const float* origin  = (const float*)d_in[1];
    const float* labels  = (const float*)d_in[2];
    const float* xs_     = (const float*)d_in[3];
    const float* ys_     = (const float*)d_in[4];
    const float* st_     = (const float*)d_in[5];
    float* out = (float*)d_out;
    char* ws = (char*)d_ws;

    int*    matchcnt = (int*)(ws);
    float*  acc      = (float*)(ws + OFF_ACC);
    float4* rec0     = (float4*)(ws + OFF_REC0);
    float4* rec1     = (float4*)(ws + OFF_REC1);
    int*    matchg   = (int*)(ws + OFF_MG);
    float*  fgarr    = (float*)(ws + OFF_FG);
    float4* geom     = (float4*)(ws + OFF_GEOM);
    float*  clsterm  = (float*)(ws + OFF_CT);

    hipMemsetAsync(ws, 0, OFF_ACC + 32, stream);

    k0_geom<<<(AA + 255) / 256, 256, 0, stream>>>(xs_, ys_, st_, geom);

    dim3 grid1((AA + 63) / 64, BB);
    k1_precompute<<<grid1, 256, 0, stream>>>(outputs, labels, geom, rec0, rec1, fgarr, clsterm);

    k2_assign<<<BB * GG, 256, 0, stream>>>(labels, geom, rec0, fgarr, clsterm, matchcnt, matchg);

    dim3 grid4((AA + 255) / 256, BB);
    k4_loss<<<grid4, 256, 0, stream>>>(outputs, origin, labels, xs_, ys_, st_, geom,
                                       rec0, rec1, clsterm, matchcnt, matchg, acc);

    k5_final<<<1, 64, 0, stream>>>(acc, out);
}

// Round 3
// 295.769 us; speedup vs baseline: 2.1729x; 1.5475x over previous
//
#include <hip/hip_runtime.h>
#include <cfloat>

#define BB 32
#define AA 8400
#define GG 40
#define NC 80
#define NO 85
#define CAP 2048   // >= hard geometric bound of 27 anchors/gt * 40 gts = 1080

// ---------- deterministic helpers: explicit _rn ops (no FMA contraction) so every
// call site produces bitwise-identical values ----------

__device__ inline bool dev_in(float gx, float gy, float xc, float yc, float r)
{
    float dl = __fsub_rn(xc, __fsub_rn(gx, r));
    float dr = __fsub_rn(__fadd_rn(gx, r), xc);
    float dt = __fsub_rn(yc, __fsub_rn(gy, r));
    float db = __fsub_rn(__fadd_rn(gy, r), yc);
    return fminf(fminf(dl, dr), fminf(dt, db)) > 0.0f;
}

// returns (cost, masked_iou); ct = precomputed class-cost term, fg = fg_anchor flag
__device__ inline float2 cost_iou(float gx, float gy, float gw, float gh,
                                  float px, float py, float pw, float ph,
                                  float xc, float yc, float r,
                                  float ct, float fg)
{
    bool in = dev_in(gx, gy, xc, yc, r);
    float gw2 = __fmul_rn(gw, 0.5f), gh2 = __fmul_rn(gh, 0.5f);
    float pw2 = __fmul_rn(pw, 0.5f), ph2 = __fmul_rn(ph, 0.5f);
    float tlx = fmaxf(__fsub_rn(gx, gw2), __fsub_rn(px, pw2));
    float tly = fmaxf(__fsub_rn(gy, gh2), __fsub_rn(py, ph2));
    float brx = fminf(__fadd_rn(gx, gw2), __fadd_rn(px, pw2));
    float bry = fminf(__fadd_rn(gy, gh2), __fadd_rn(py, ph2));
    float en = (tlx < brx && tly < bry) ? 1.0f : 0.0f;
    float ai = __fmul_rn(__fmul_rn(__fsub_rn(brx, tlx), __fsub_rn(bry, tly)), en);
    float ag = __fmul_rn(gw, gh);
    float ap = __fmul_rn(pw, ph);
    float iou = ai / __fsub_rn(__fadd_rn(ag, ap), ai);
    iou = (fg != 0.0f) ? iou : 0.0f;
    float icost = -__logf(__fadd_rn(iou, 1e-8f));
    float cost = __fadd_rn(__fadd_rn(ct, __fmul_rn(3.0f, icost)), in ? 0.0f : 1000000.0f);
    cost = (fg != 0.0f) ? cost : 1000000000.0f;
    return make_float2(cost, iou);
}

__device__ inline float wave_sum(float v)
{
#pragma unroll
    for (int o = 32; o > 0; o >>= 1) v += __shfl_down(v, o, 64);
    return v;
}

// ---------- K0: per-anchor geometry (xc, yc, r, st) ----------
__global__ __launch_bounds__(256) void k0_geom(
    const float* __restrict__ xs_, const float* __restrict__ ys_, const float* __restrict__ st_,
    float4* __restrict__ geom)
{
    int a = blockIdx.x * 256 + threadIdx.x;
    if (a < AA) {
        float st = st_[a];
        float xc = __fmul_rn(__fadd_rn(xs_[a], 0.5f), st);
        float yc = __fmul_rn(__fadd_rn(ys_[a], 0.5f), st);
        float r  = __fmul_rn(1.5f, st);
        geom[a] = make_float4(xc, yc, r, st);
    }
}

// ---------- K1a: all anchors — fg flag + compact list + obj-BCE base sum ----------
__global__ __launch_bounds__(256) void k1a_fg(
    const float* __restrict__ outputs, const float* __restrict__ labels,
    const float4* __restrict__ geom,
    int* __restrict__ alist, int* __restrict__ inv, int* __restrict__ cnt,
    float* __restrict__ acc)
{
    int b = blockIdx.y;
    int a = blockIdx.x * 256 + threadIdx.x;
    __shared__ float lgt[GG * 5];
    for (int i = threadIdx.x; i < GG * 5; i += 256) lgt[i] = labels[b * GG * 5 + i];
    __syncthreads();

    float sp = 0.0f;
    if (a < AA) {
        size_t idx = (size_t)b * AA + a;
        float obj = outputs[idx * NO + 4];
        sp = fmaxf(obj, 0.0f) + __logf(1.0f + __expf(-fabsf(obj)));  // BCE(obj, t=0)
        float4 gm = geom[a];
        bool fg = false;
        for (int g = 0; g < GG && !fg; g++)
            fg = dev_in(lgt[g * 5 + 1], lgt[g * 5 + 2], gm.x, gm.y, gm.z);
        if (fg) {
            int i = atomicAdd(&cnt[b], 1);
            if (i < CAP) { alist[b * CAP + i] = a; inv[idx] = i; }
        }
    }
    sp = wave_sum(sp);
    __shared__ float red[4];
    if ((threadIdx.x & 63) == 0) red[threadIdx.x >> 6] = sp;
    __syncthreads();
    if (threadIdx.x == 0) atomicAdd(&acc[2], red[0] + red[1] + red[2] + red[3]);
}

// ---------- K1b: fg anchors only — class terms + compacted records ----------
__global__ __launch_bounds__(256) void k1b_cls(
    const float* __restrict__ outputs, const float* __restrict__ labels,
    const float4* __restrict__ geom,
    const int* __restrict__ alist, const int* __restrict__ cnt,
    float4* __restrict__ blist, float4* __restrict__ glist, float* __restrict__ clsterm)
{
    int b = blockIdx.y;
    __shared__ float lgt[GG * 5];
    for (int t = threadIdx.x; t < GG * 5; t += 256) lgt[t] = labels[b * GG * 5 + t];
    __syncthreads();

    int n = cnt[b]; n = n > CAP ? CAP : n;
    int i = blockIdx.x * 256 + threadIdx.x;
    if (i >= n) return;
    int a = alist[b * CAP + i];
    size_t idx = (size_t)b * AA + a;
    const float* o = outputs + idx * NO;
    float obj = o[4];

    float s1 = 0.0f;
    for (int c = 0; c < NC; c++) {
        float m = __fmul_rn(o[5 + c], obj);
        float p = __fsqrt_rn(m);
        s1 += __logf(__fsub_rn(1.0f, p));       // log1p(-p), p in [0.02, 0.98]
    }
    float nsl = -s1;

    blist[b * CAP + i] = make_float4(o[0], o[1], o[2], o[3]);
    glist[b * CAP + i] = geom[a];
    for (int g = 0; g < GG; g++) {
        int gc = (int)lgt[g * 5];
        float m = __fmul_rn(o[5 + gc], obj);
        float p = __fsqrt_rn(m);
        float term = __fsub_rn(__fmul_rn(0.5f, __logf(m)), __logf(__fsub_rn(1.0f, p)));
        clsterm[((size_t)b * GG + g) * CAP + i] = __fsub_rn(nsl, term);   // coalesced over i
    }
}

// ---------- K2: per-(b,g) SimOTA over compacted fg list ----------
__global__ __launch_bounds__(256) void k2_assign(
    const float* __restrict__ labels,
    const int* __restrict__ alist, const int* __restrict__ cnt,
    const float4* __restrict__ blist, const float4* __restrict__ glist,
    const float* __restrict__ clsterm,
    int* __restrict__ matchcnt, int* __restrict__ matchg)
{
    int g = blockIdx.x, b = blockIdx.y;
    int tid = threadIdx.x;
    const float* L = labels + (b * GG + g) * 5;
    float gx = L[1], gy = L[2], gw = L[3], gh = L[4];
    int n = cnt[b]; n = n > CAP ? CAP : n;

    const float*  ctp = clsterm + ((size_t)b * GG + g) * CAP;
    const float4* bp  = blist + b * CAP;
    const float4* gp  = glist + b * CAP;
    const int*    ap  = alist + b * CAP;

    float tc[10]; int ti[10]; float tv[10];
#pragma unroll
    for (int k = 0; k < 10; k++) { tc[k] = FLT_MAX; ti[k] = 0x7FFFFFFF; tv[k] = 0.0f; }

    for (int i = tid; i < n; i += 256) {
        float4 pb = bp[i];
        float4 gm = gp[i];
        float2 ci = cost_iou(gx, gy, gw, gh, pb.x, pb.y, pb.z, pb.w,
                             gm.x, gm.y, gm.z, ctp[i], 1.0f);
        float c = ci.x, v = ci.y;
        int a = ap[i];
        if (c < tc[9] || (c == tc[9] && a < ti[9])) {
            int p = 0;
#pragma unroll
            for (int k = 0; k < 10; k++) p += ((tc[k] < c) || (tc[k] == c && ti[k] < a)) ? 1 : 0;
#pragma unroll
            for (int k = 9; k >= 1; k--) {
                bool sh = (k > p);
                tc[k] = sh ? tc[k - 1] : tc[k];
                ti[k] = sh ? ti[k - 1] : ti[k];
            }
#pragma unroll
            for (int k = 0; k < 10; k++) if (k == p) { tc[k] = c; ti[k] = a; }
        }
        if (v > tv[9]) {
            int p = 0;
#pragma unroll
            for (int k = 0; k < 10; k++) p += (tv[k] > v) ? 1 : 0;
#pragma unroll
            for (int k = 9; k >= 1; k--) { bool sh = (k > p); tv[k] = sh ? tv[k - 1] : tv[k]; }
#pragma unroll
            for (int k = 0; k < 10; k++) if (k == p) tv[k] = v;
        }
    }

    __shared__ float sc[256 * 10];
    __shared__ int   si[256 * 10];
    __shared__ float sv[256 * 10];
#pragma unroll
    for (int k = 0; k < 10; k++) { sc[tid * 10 + k] = tc[k]; si[tid * 10 + k] = ti[k]; sv[tid * 10 + k] = tv[k]; }
    __syncthreads();

    for (int s = 128; s > 0; s >>= 1) {
        if (tid < s) {
            int pa = tid * 10, pb2 = (tid + s) * 10;
            float mc[10]; int mi[10]; float mv[10];
            int ia = 0, ib = 0;
#pragma unroll
            for (int k = 0; k < 10; k++) {
                bool ta;
                if (ia >= 10) ta = false;
                else if (ib >= 10) ta = true;
                else {
                    float ca = sc[pa + ia], cb = sc[pb2 + ib];
                    ta = (ca < cb) || (ca == cb && si[pa + ia] < si[pb2 + ib]);
                }
                if (ta) { mc[k] = sc[pa + ia]; mi[k] = si[pa + ia]; ia++; }
                else    { mc[k] = sc[pb2 + ib]; mi[k] = si[pb2 + ib]; ib++; }
            }
            ia = 0; ib = 0;
#pragma unroll
            for (int k = 0; k < 10; k++) {
                bool ta;
                if (ia >= 10) ta = false;
                else if (ib >= 10) ta = true;
                else ta = (sv[pa + ia] >= sv[pb2 + ib]);
                if (ta) { mv[k] = sv[pa + ia]; ia++; }
                else    { mv[k] = sv[pb2 + ib]; ib++; }
            }
#pragma unroll
            for (int k = 0; k < 10; k++) { sc[pa + k] = mc[k]; si[pa + k] = mi[k]; sv[pa + k] = mv[k]; }
        }
        __syncthreads();
    }

    if (tid == 0) {
        float sum = 0.0f;
#pragma unroll
        for (int k = 0; k < 10; k++) sum += sv[k];
        int dk = (int)sum;
        dk = dk < 1 ? 1 : (dk > 10 ? 10 : dk);
        for (int k = 0; k < dk; k++) {
            int a = si[k];
            if ((unsigned)a < AA) {
                atomicAdd(&matchcnt[(size_t)b * AA + a], 1);
                atomicExch(&matchg[(size_t)b * AA + a], g);
            }
        }
    }
}

// ---------- K4: resolve multi-match + loss terms ----------
__global__ __launch_bounds__(256) void k4_loss(
    const float* __restrict__ outputs, const float* __restrict__ origin,
    const float* __restrict__ labels,
    const float* __restrict__ xs_, const float* __restrict__ ys_, const float* __restrict__ st_,
    const float4* __restrict__ geom,
    const float* __restrict__ clsterm, const int* __restrict__ inv,
    const int* __restrict__ matchcnt, const int* __restrict__ matchg,
    float* __restrict__ acc)
{
    int b = blockIdx.y;
    int a = blockIdx.x * blockDim.x + threadIdx.x;
    __shared__ float lgt[GG * 5];
    for (int i = threadIdx.x; i < GG * 5; i += blockDim.x) lgt[i] = labels[b * GG * 5 + i];
    __syncthreads();

    float t_fg = 0.0f, t_iou = 0.0f, t_obj = 0.0f, t_cls = 0.0f, t_l1 = 0.0f;
    if (a < AA) {
        size_t idx = (size_t)b * AA + a;
        int mcnt = matchcnt[idx];
        if (mcnt > 0) {
            const float* o = outputs + idx * NO;
            float obj = o[4];
            t_obj = -obj;                    // BCE(x,1) - BCE(x,0); base summed in K1a
            t_fg = 1.0f;
            float4 pb = make_float4(o[0], o[1], o[2], o[3]);
            float4 gm = geom[a];
            int ci = inv[idx];
            int mg;
            if (mcnt == 1) {
                mg = matchg[idx];
            } else {
                mg = 0; float best = FLT_MAX;
                for (int g = 0; g < GG; g++) {
                    float ct = clsterm[((size_t)b * GG + g) * CAP + ci];
                    float2 r = cost_iou(lgt[g * 5 + 1], lgt[g * 5 + 2], lgt[g * 5 + 3], lgt[g * 5 + 4],
                                        pb.x, pb.y, pb.z, pb.w, gm.x, gm.y, gm.z, ct, 1.0f);
                    if (r.x < best) { best = r.x; mg = g; }
                }
            }
            float gx = lgt[mg * 5 + 1], gy = lgt[mg * 5 + 2], gw = lgt[mg * 5 + 3], gh = lgt[mg * 5 + 4];
            int mcls = (int)lgt[mg * 5];
            float ctm = clsterm[((size_t)b * GG + mg) * CAP + ci];
            float2 r = cost_iou(gx, gy, gw, gh, pb.x, pb.y, pb.z, pb.w, gm.x, gm.y, gm.z, ctm, 1.0f);
            float pred_iou = r.y;
            // iou_elem (loss path, 1e-16 eps)
            float tlx = fmaxf(pb.x - pb.z * 0.5f, gx - gw * 0.5f);
            float tly = fmaxf(pb.y - pb.w * 0.5f, gy - gh * 0.5f);
            float brx = fminf(pb.x + pb.z * 0.5f, gx + gw * 0.5f);
            float bry = fminf(pb.y + pb.w * 0.5f, gy + gh * 0.5f);
            float en = (tlx < brx && tly < bry) ? 1.0f : 0.0f;
            float ai = (brx - tlx) * (bry - tly) * en;
            float iou = ai / (pb.z * pb.w + gw * gh - ai + 1e-16f);
            t_iou = 1.0f - iou * iou;
            const float* op = origin + idx * 4;
            float stv = st_[a], xsv = xs_[a], ysv = ys_[a];
            t_l1 = fabsf(op[0] - (gx / stv - xsv)) + fabsf(op[1] - (gy / stv - ysv))
                 + fabsf(op[2] - logf(gw / stv + 1e-8f)) + fabsf(op[3] - logf(gh / stv + 1e-8f));
            float sbce = 0.0f;
            for (int c = 0; c < NC; c++) {
                float x = o[5 + c];
                sbce += fmaxf(x, 0.0f) + __logf(1.0f + __expf(-fabsf(x)));
            }
            t_cls = sbce - o[5 + mcls] * pred_iou;
        }
    }

    t_fg = wave_sum(t_fg); t_iou = wave_sum(t_iou); t_obj = wave_sum(t_obj);
    t_cls = wave_sum(t_cls); t_l1 = wave_sum(t_l1);
    __shared__ float red[5][4];
    int wv = threadIdx.x >> 6, ln = threadIdx.x & 63;
    if (ln == 0) { red[0][wv] = t_fg; red[1][wv] = t_iou; red[2][wv] = t_obj; red[3][wv] = t_cls; red[4][wv] = t_l1; }
    __syncthreads();
    if (threadIdx.x == 0) {
        atomicAdd(&acc[0], red[0][0] + red[0][1] + red[0][2] + red[0][3]);
        atomicAdd(&acc[1], red[1][0] + red[1][1] + red[1][2] + red[1][3]);
        atomicAdd(&acc[2], red[2][0] + red[2][1] + red[2][2] + red[2][3]);
        atomicAdd(&acc[3], red[3][0] + red[3][1] + red[3][2] + red[3][3]);
        atomicAdd(&acc[4], red[4][0] + red[4][1] + red[4][2] + red[4][3]);
    }
}

// ---------- K5: finalize ----------
__global__ void k5_final(const float* __restrict__ acc, float* __restrict__ out)
{
    if (threadIdx.x == 0 && blockIdx.x == 0) {
        float nfg = fmaxf(acc[0], 1.0f);
        float li = 5.0f * acc[1] / nfg;
        float lo = acc[2] / nfg;
        float lc = acc[3] / nfg;
        float ll = acc[4] / nfg;
        out[0] = li + lo + lc + ll;
        out[1] = li;
        out[2] = lo;
        out[3] = lc;
        out[4] = ll;
        out[5] = nfg / (float)(BB * GG);
    }
}

// ---------- workspace layout (all offsets 16B-aligned) ----------
static constexpr size_t NBA       = (size_t)BB * AA;                 // 268800
static constexpr size_t OFF_ACC   = NBA * 4;                         // matchcnt first
static constexpr size_t OFF_CNT   = OFF_ACC + 32;                    // acc[8]
static constexpr size_t OFF_GEOM  = OFF_CNT + 128;                   // cnt[32]
static constexpr size_t OFF_ALIST = OFF_GEOM + (size_t)AA * 16;
static constexpr size_t OFF_INV   = OFF_ALIST + (size_t)BB * CAP * 4;
static constexpr size_t OFF_BL    = OFF_INV + NBA * 4;
static constexpr size_t OFF_GL    = OFF_BL + (size_t)BB * CAP * 16;
static constexpr size_t OFF_CT    = OFF_GL + (size_t)BB * CAP * 16;
static constexpr size_t OFF_MG    = OFF_CT + (size_t)BB * GG * CAP * 4;
// total ≈ 16 MB

extern "C" void kernel_launch(void* const* d_in, const int* in_sizes, int n_in,
                              void* d_out, int out_size, void* d_ws, size_t ws_size,
                              hipStream_t stream)
{
    (void)in_sizes; (void)n_in; (void)out_size; (void)ws_size;
    const float* outputs = (const float*)d_in[0];
    const float* origin  = (const float*)d_in[1];
    const float* labels  = (const float*)d_in[2];
    const float* xs_     = (const float*)d_in[3];
    const float* ys_     = (const float*)d_in[4];
    const float* st_     = (const float*)d_in[5];
    float* out = (float*)d_out;
    char* ws = (char*)d_ws;

    int*    matchcnt = (int*)(ws);
    float*  acc      = (float*)(ws + OFF_ACC);
    int*    cnt      = (int*)(ws + OFF_CNT);
    float4* geom     = (float4*)(ws + OFF_GEOM);
    int*    alist    = (int*)(ws + OFF_ALIST);
    int*    inv      = (int*)(ws + OFF_INV);
    float4* blist    = (float4*)(ws + OFF_BL);
    float4* glist    = (float4*)(ws + OFF_GL);
    float*  clsterm  = (float*)(ws + OFF_CT);
    int*    matchg   = (int*)(ws + OFF_MG);

    hipMemsetAsync(ws, 0, OFF_GEOM, stream);   // matchcnt + acc + cnt

    k0_geom<<<(AA + 255) / 256, 256, 0, stream>>>(xs_, ys_, st_, geom);

    dim3 grid1((AA + 255) / 256, BB);
    k1a_fg<<<grid1, 256, 0, stream>>>(outputs, labels, geom, alist, inv, cnt, acc);

    dim3 grid1b(CAP / 256, BB);
    k1b_cls<<<grid1b, 256, 0, stream>>>(outputs, labels, geom, alist, cnt, blist, glist, clsterm);

    dim3 grid2(GG, BB);
    k2_assign<<<grid2, 256, 0, stream>>>(labels, alist, cnt, blist, glist, clsterm, matchcnt, matchg);

    k4_loss<<<grid1, 256, 0, stream>>>(outputs, origin, labels, xs_, ys_, st_, geom,
                                       clsterm, inv, matchcnt, matchg, acc);

    k5_final<<<1, 64, 0, stream>>>(acc, out);
}

// Round 4
// 267.725 us; speedup vs baseline: 2.4005x; 1.1047x over previous
//
#include <hip/hip_runtime.h>
#include <cfloat>

#define BB 32
#define AA 8400
#define GG 40
#define NC 80
#define NO 85
#define CAP 2048    // >= geometric bound ~27 anchors/gt * 40 gts = 1080
#define CAPW 13312  // >= 1280 gts * dk_max 10 = 12800

// ---------- deterministic helpers: explicit _rn ops (no FMA contraction) so every
// call site produces bitwise-identical values ----------

__device__ inline bool dev_in(float gx, float gy, float xc, float yc, float r)
{
    float dl = __fsub_rn(xc, __fsub_rn(gx, r));
    float dr = __fsub_rn(__fadd_rn(gx, r), xc);
    float dt = __fsub_rn(yc, __fsub_rn(gy, r));
    float db = __fsub_rn(__fadd_rn(gy, r), yc);
    return fminf(fminf(dl, dr), fminf(dt, db)) > 0.0f;
}

// returns (cost, masked_iou); ct = precomputed class-cost term, fg = fg_anchor flag
__device__ inline float2 cost_iou(float gx, float gy, float gw, float gh,
                                  float px, float py, float pw, float ph,
                                  float xc, float yc, float r,
                                  float ct, float fg)
{
    bool in = dev_in(gx, gy, xc, yc, r);
    float gw2 = __fmul_rn(gw, 0.5f), gh2 = __fmul_rn(gh, 0.5f);
    float pw2 = __fmul_rn(pw, 0.5f), ph2 = __fmul_rn(ph, 0.5f);
    float tlx = fmaxf(__fsub_rn(gx, gw2), __fsub_rn(px, pw2));
    float tly = fmaxf(__fsub_rn(gy, gh2), __fsub_rn(py, ph2));
    float brx = fminf(__fadd_rn(gx, gw2), __fadd_rn(px, pw2));
    float bry = fminf(__fadd_rn(gy, gh2), __fadd_rn(py, ph2));
    float en = (tlx < brx && tly < bry) ? 1.0f : 0.0f;
    float ai = __fmul_rn(__fmul_rn(__fsub_rn(brx, tlx), __fsub_rn(bry, tly)), en);
    float ag = __fmul_rn(gw, gh);
    float ap = __fmul_rn(pw, ph);
    float iou = ai / __fsub_rn(__fadd_rn(ag, ap), ai);
    iou = (fg != 0.0f) ? iou : 0.0f;
    float icost = -__logf(__fadd_rn(iou, 1e-8f));
    float cost = __fadd_rn(__fadd_rn(ct, __fmul_rn(3.0f, icost)), in ? 0.0f : 1000000.0f);
    cost = (fg != 0.0f) ? cost : 1000000000.0f;
    return make_float2(cost, iou);
}

__device__ inline float wave_sum(float v)
{
#pragma unroll
    for (int o = 32; o > 0; o >>= 1) v += __shfl_down(v, o, 64);
    return v;
}

// ---------- K0: per-anchor geometry (xc, yc, r, st) ----------
__global__ __launch_bounds__(256) void k0_geom(
    const float* __restrict__ xs_, const float* __restrict__ ys_, const float* __restrict__ st_,
    float4* __restrict__ geom)
{
    int a = blockIdx.x * 256 + threadIdx.x;
    if (a < AA) {
        float st = st_[a];
        float xc = __fmul_rn(__fadd_rn(xs_[a], 0.5f), st);
        float yc = __fmul_rn(__fadd_rn(ys_[a], 0.5f), st);
        float r  = __fmul_rn(1.5f, st);
        geom[a] = make_float4(xc, yc, r, st);
    }
}

// ---------- K1a: all anchors — fg flag + compact list + obj-BCE base sum ----------
__global__ __launch_bounds__(256) void k1a_fg(
    const float* __restrict__ outputs, const float* __restrict__ labels,
    const float4* __restrict__ geom,
    int* __restrict__ alist, int* __restrict__ cnt,
    float* __restrict__ acc)
{
    int b = blockIdx.y;
    int a = blockIdx.x * 256 + threadIdx.x;
    __shared__ float lgt[GG * 5];
    for (int i = threadIdx.x; i < GG * 5; i += 256) lgt[i] = labels[b * GG * 5 + i];
    __syncthreads();

    float sp = 0.0f;
    if (a < AA) {
        size_t idx = (size_t)b * AA + a;
        float obj = outputs[idx * NO + 4];
        sp = fmaxf(obj, 0.0f) + __logf(1.0f + __expf(-fabsf(obj)));  // BCE(obj, t=0)
        float4 gm = geom[a];
        bool fg = false;
        for (int g = 0; g < GG && !fg; g++)
            fg = dev_in(lgt[g * 5 + 1], lgt[g * 5 + 2], gm.x, gm.y, gm.z);
        if (fg) {
            int i = atomicAdd(&cnt[b], 1);
            if (i < CAP) alist[b * CAP + i] = a;
        }
    }
    sp = wave_sum(sp);
    __shared__ float red[4];
    if ((threadIdx.x & 63) == 0) red[threadIdx.x >> 6] = sp;
    __syncthreads();
    if (threadIdx.x == 0) atomicAdd(&acc[2], red[0] + red[1] + red[2] + red[3]);
}

// ---------- K1b: fg anchors only — class terms + compacted records ----------
__global__ __launch_bounds__(256) void k1b_cls(
    const float* __restrict__ outputs, const float* __restrict__ labels,
    const float4* __restrict__ geom,
    const int* __restrict__ alist, const int* __restrict__ cnt,
    float4* __restrict__ blist, float4* __restrict__ glist,
    float2* __restrict__ misc, float* __restrict__ clsterm)
{
    int b = blockIdx.y;
    __shared__ float lgt[GG * 5];
    for (int t = threadIdx.x; t < GG * 5; t += 256) lgt[t] = labels[b * GG * 5 + t];
    __syncthreads();

    int n = cnt[b]; n = n > CAP ? CAP : n;
    int i = blockIdx.x * 256 + threadIdx.x;
    if (i >= n) return;
    int a = alist[b * CAP + i];
    size_t idx = (size_t)b * AA + a;
    const float* o = outputs + idx * NO;
    float obj = o[4];

    float s1 = 0.0f, s2 = 0.0f;
    for (int c = 0; c < NC; c++) {
        float x = o[5 + c];
        float m = __fmul_rn(x, obj);
        float p = __fsqrt_rn(m);
        s1 += __logf(__fsub_rn(1.0f, p));                      // log1p(-p), p in [0.02,0.98]
        s2 += fmaxf(x, 0.0f) + __logf(1.0f + __expf(-fabsf(x)));  // softplus BCE base
    }
    float nsl = -s1;

    blist[b * CAP + i] = make_float4(o[0], o[1], o[2], o[3]);
    glist[b * CAP + i] = geom[a];
    misc[b * CAP + i]  = make_float2(s2, obj);
    for (int g = 0; g < GG; g++) {
        int gc = (int)lgt[g * 5];
        float m = __fmul_rn(o[5 + gc], obj);
        float p = __fsqrt_rn(m);
        float term = __fsub_rn(__fmul_rn(0.5f, __logf(m)), __logf(__fsub_rn(1.0f, p)));
        clsterm[((size_t)b * GG + g) * CAP + i] = __fsub_rn(nsl, term);   // coalesced over i
    }
}

// ---------- K2: per-(b,g) SimOTA over compacted fg list; builds matched worklist ----------
// top-10 key packs (anchor<<11)|compact_i : compare order == compare by anchor id.
__global__ __launch_bounds__(256) void k2_assign(
    const float* __restrict__ labels,
    const int* __restrict__ alist, const int* __restrict__ cnt,
    const float4* __restrict__ blist, const float4* __restrict__ glist,
    const float* __restrict__ clsterm,
    int* __restrict__ matchcnt, int2* __restrict__ wl, int* __restrict__ wlcnt)
{
    int g = blockIdx.x, b = blockIdx.y;
    int tid = threadIdx.x;
    const float* L = labels + (b * GG + g) * 5;
    float gx = L[1], gy = L[2], gw = L[3], gh = L[4];
    int n = cnt[b]; n = n > CAP ? CAP : n;

    const float*  ctp = clsterm + ((size_t)b * GG + g) * CAP;
    const float4* bp  = blist + b * CAP;
    const float4* gp  = glist + b * CAP;
    const int*    ap  = alist + b * CAP;

    float tc[10]; int ti[10]; float tv[10];
#pragma unroll
    for (int k = 0; k < 10; k++) { tc[k] = FLT_MAX; ti[k] = 0x7FFFFFFF; tv[k] = 0.0f; }

    for (int i = tid; i < n; i += 256) {
        float4 pb = bp[i];
        float4 gm = gp[i];
        float2 ci = cost_iou(gx, gy, gw, gh, pb.x, pb.y, pb.z, pb.w,
                             gm.x, gm.y, gm.z, ctp[i], 1.0f);
        float c = ci.x, v = ci.y;
        int key = (ap[i] << 11) | i;
        if (c < tc[9] || (c == tc[9] && key < ti[9])) {
            int p = 0;
#pragma unroll
            for (int k = 0; k < 10; k++) p += ((tc[k] < c) || (tc[k] == c && ti[k] < key)) ? 1 : 0;
#pragma unroll
            for (int k = 9; k >= 1; k--) {
                bool sh = (k > p);
                tc[k] = sh ? tc[k - 1] : tc[k];
                ti[k] = sh ? ti[k - 1] : ti[k];
            }
#pragma unroll
            for (int k = 0; k < 10; k++) if (k == p) { tc[k] = c; ti[k] = key; }
        }
        if (v > tv[9]) {
            int p = 0;
#pragma unroll
            for (int k = 0; k < 10; k++) p += (tv[k] > v) ? 1 : 0;
#pragma unroll
            for (int k = 9; k >= 1; k--) { bool sh = (k > p); tv[k] = sh ? tv[k - 1] : tv[k]; }
#pragma unroll
            for (int k = 0; k < 10; k++) if (k == p) tv[k] = v;
        }
    }

    __shared__ float sc[256 * 10];
    __shared__ int   si[256 * 10];
    __shared__ float sv[256 * 10];
#pragma unroll
    for (int k = 0; k < 10; k++) { sc[tid * 10 + k] = tc[k]; si[tid * 10 + k] = ti[k]; sv[tid * 10 + k] = tv[k]; }
    __syncthreads();

    for (int s = 128; s > 0; s >>= 1) {
        if (tid < s) {
            int pa = tid * 10, pb2 = (tid + s) * 10;
            float mc[10]; int mi[10]; float mv[10];
            int ia = 0, ib = 0;
#pragma unroll
            for (int k = 0; k < 10; k++) {
                bool ta;
                if (ia >= 10) ta = false;
                else if (ib >= 10) ta = true;
                else {
                    float ca = sc[pa + ia], cb = sc[pb2 + ib];
                    ta = (ca < cb) || (ca == cb && si[pa + ia] < si[pb2 + ib]);
                }
                if (ta) { mc[k] = sc[pa + ia]; mi[k] = si[pa + ia]; ia++; }
                else    { mc[k] = sc[pb2 + ib]; mi[k] = si[pb2 + ib]; ib++; }
            }
            ia = 0; ib = 0;
#pragma unroll
            for (int k = 0; k < 10; k++) {
                bool ta;
                if (ia >= 10) ta = false;
                else if (ib >= 10) ta = true;
                else ta = (sv[pa + ia] >= sv[pb2 + ib]);
                if (ta) { mv[k] = sv[pa + ia]; ia++; }
                else    { mv[k] = sv[pb2 + ib]; ib++; }
            }
#pragma unroll
            for (int k = 0; k < 10; k++) { sc[pa + k] = mc[k]; si[pa + k] = mi[k]; sv[pa + k] = mv[k]; }
        }
        __syncthreads();
    }

    if (tid == 0) {
        float sum = 0.0f;
#pragma unroll
        for (int k = 0; k < 10; k++) sum += sv[k];
        int dk = (int)sum;
        dk = dk < 1 ? 1 : (dk > 10 ? 10 : dk);
        for (int k = 0; k < dk; k++) {
            int key = si[k];
            int a = key >> 11;
            int i2 = key & 2047;
            if ((unsigned)a < AA) {
                int idx = b * AA + a;
                int old = atomicAdd(&matchcnt[idx], 1);
                if (old == 0) {
                    int w = atomicAdd(wlcnt, 1);
                    if (w < CAPW) wl[w] = make_int2(idx, (g << 16) | i2);
                }
            }
        }
    }
}

// ---------- K4: dense loss over matched-anchor worklist ----------
__global__ __launch_bounds__(256) void k4_loss(
    const float* __restrict__ outputs, const float* __restrict__ origin,
    const float* __restrict__ labels,
    const float* __restrict__ xs_, const float* __restrict__ ys_, const float* __restrict__ st_,
    const float4* __restrict__ blist, const float4* __restrict__ glist,
    const float2* __restrict__ misc, const float* __restrict__ clsterm,
    const int* __restrict__ matchcnt,
    const int2* __restrict__ wl, const int* __restrict__ wlcnt,
    float* __restrict__ acc)
{
    int t = blockIdx.x * 256 + threadIdx.x;
    int nw = *wlcnt; nw = nw > CAPW ? CAPW : nw;

    float t_fg = 0.0f, t_iou = 0.0f, t_obj = 0.0f, t_cls = 0.0f, t_l1 = 0.0f;
    if (t < nw) {
        int2 e = wl[t];
        int idx = e.x;
        int b = idx / AA;
        int a = idx - b * AA;
        int ci = e.y & 0xFFFF;
        int g1 = e.y >> 16;
        int mcnt = matchcnt[idx];

        float4 pb = blist[b * CAP + ci];
        float4 gm = glist[b * CAP + ci];
        float2 mo = misc[b * CAP + ci];   // (sbce, obj)
        const float* Lb = labels + b * GG * 5;

        int mg;
        if (mcnt == 1) {
            mg = g1;
        } else {
            mg = 0; float best = FLT_MAX;
            for (int g = 0; g < GG; g++) {
                float ct = clsterm[((size_t)b * GG + g) * CAP + ci];
                float2 r = cost_iou(Lb[g * 5 + 1], Lb[g * 5 + 2], Lb[g * 5 + 3], Lb[g * 5 + 4],
                                    pb.x, pb.y, pb.z, pb.w, gm.x, gm.y, gm.z, ct, 1.0f);
                if (r.x < best) { best = r.x; mg = g; }
            }
        }
        t_fg = 1.0f;
        t_obj = -mo.y;   // BCE(x,1)-BCE(x,0); base summed in K1a
        float gx = Lb[mg * 5 + 1], gy = Lb[mg * 5 + 2], gw = Lb[mg * 5 + 3], gh = Lb[mg * 5 + 4];
        int mcls = (int)Lb[mg * 5];
        float ctm = clsterm[((size_t)b * GG + mg) * CAP + ci];
        float2 r = cost_iou(gx, gy, gw, gh, pb.x, pb.y, pb.z, pb.w, gm.x, gm.y, gm.z, ctm, 1.0f);
        float pred_iou = r.y;
        // iou_elem (loss path, 1e-16 eps)
        float tlx = fmaxf(pb.x - pb.z * 0.5f, gx - gw * 0.5f);
        float tly = fmaxf(pb.y - pb.w * 0.5f, gy - gh * 0.5f);
        float brx = fminf(pb.x + pb.z * 0.5f, gx + gw * 0.5f);
        float bry = fminf(pb.y + pb.w * 0.5f, gy + gh * 0.5f);
        float en = (tlx < brx && tly < bry) ? 1.0f : 0.0f;
        float ai = (brx - tlx) * (bry - tly) * en;
        float iou = ai / (pb.z * pb.w + gw * gh - ai + 1e-16f);
        t_iou = 1.0f - iou * iou;
        const float* op = origin + (size_t)idx * 4;
        float stv = st_[a], xsv = xs_[a], ysv = ys_[a];
        t_l1 = fabsf(op[0] - (gx / stv - xsv)) + fabsf(op[1] - (gy / stv - ysv))
             + fabsf(op[2] - logf(gw / stv + 1e-8f)) + fabsf(op[3] - logf(gh / stv + 1e-8f));
        t_cls = mo.x - outputs[(size_t)idx * NO + 5 + mcls] * pred_iou;
    }

    t_fg = wave_sum(t_fg); t_iou = wave_sum(t_iou); t_obj = wave_sum(t_obj);
    t_cls = wave_sum(t_cls); t_l1 = wave_sum(t_l1);
    __shared__ float red[5][4];
    int wv = threadIdx.x >> 6, ln = threadIdx.x & 63;
    if (ln == 0) { red[0][wv] = t_fg; red[1][wv] = t_iou; red[2][wv] = t_obj; red[3][wv] = t_cls; red[4][wv] = t_l1; }
    __syncthreads();
    if (threadIdx.x == 0) {
        atomicAdd(&acc[0], red[0][0] + red[0][1] + red[0][2] + red[0][3]);
        atomicAdd(&acc[1], red[1][0] + red[1][1] + red[1][2] + red[1][3]);
        atomicAdd(&acc[2], red[2][0] + red[2][1] + red[2][2] + red[2][3]);
        atomicAdd(&acc[3], red[3][0] + red[3][1] + red[3][2] + red[3][3]);
        atomicAdd(&acc[4], red[4][0] + red[4][1] + red[4][2] + red[4][3]);
    }
}

// ---------- K5: finalize ----------
__global__ void k5_final(const float* __restrict__ acc, float* __restrict__ out)
{
    if (threadIdx.x == 0 && blockIdx.x == 0) {
        float nfg = fmaxf(acc[0], 1.0f);
        float li = 5.0f * acc[1] / nfg;
        float lo = acc[2] / nfg;
        float lc = acc[3] / nfg;
        float ll = acc[4] / nfg;
        out[0] = li + lo + lc + ll;
        out[1] = li;
        out[2] = lo;
        out[3] = lc;
        out[4] = ll;
        out[5] = nfg / (float)(BB * GG);
    }
}

// ---------- workspace layout (16B-aligned blocks) ----------
static constexpr size_t NBA       = (size_t)BB * AA;                 // 268800
static constexpr size_t OFF_ACC   = NBA * 4;                         // matchcnt first
static constexpr size_t OFF_CNT   = OFF_ACC + 32;                    // acc[8]
static constexpr size_t OFF_WLC   = OFF_CNT + 128;                   // cnt[32]
static constexpr size_t OFF_GEOM  = OFF_WLC + 32;                    // wlcnt
static constexpr size_t OFF_ALIST = OFF_GEOM + (size_t)AA * 16;
static constexpr size_t OFF_BL    = OFF_ALIST + (size_t)BB * CAP * 4;
static constexpr size_t OFF_GL    = OFF_BL + (size_t)BB * CAP * 16;
static constexpr size_t OFF_MISC  = OFF_GL + (size_t)BB * CAP * 16;
static constexpr size_t OFF_CT    = OFF_MISC + (size_t)BB * CAP * 8;
static constexpr size_t OFF_WL    = OFF_CT + (size_t)BB * GG * CAP * 4;
// total = OFF_WL + CAPW*8 ≈ 16 MB

extern "C" void kernel_launch(void* const* d_in, const int* in_sizes, int n_in,
                              void* d_out, int out_size, void* d_ws, size_t ws_size,
                              hipStream_t stream)
{
    (void)in_sizes; (void)n_in; (void)out_size; (void)ws_size;
    const float* outputs = (const float*)d_in[0];
    const float* origin  = (const float*)d_in[1];
    const float* labels  = (const float*)d_in[2];
    const float* xs_     = (const float*)d_in[3];
    const float* ys_     = (const float*)d_in[4];
    const float* st_     = (const float*)d_in[5];
    float* out = (float*)d_out;
    char* ws = (char*)d_ws;

    int*    matchcnt = (int*)(ws);
    float*  acc      = (float*)(ws + OFF_ACC);
    int*    cnt      = (int*)(ws + OFF_CNT);
    int*    wlcnt    = (int*)(ws + OFF_WLC);
    float4* geom     = (float4*)(ws + OFF_GEOM);
    int*    alist    = (int*)(ws + OFF_ALIST);
    float4* blist    = (float4*)(ws + OFF_BL);
    float4* glist    = (float4*)(ws + OFF_GL);
    float2* misc     = (float2*)(ws + OFF_MISC);
    float*  clsterm  = (float*)(ws + OFF_CT);
    int2*   wl       = (int2*)(ws + OFF_WL);

    hipMemsetAsync(ws, 0, OFF_GEOM, stream);   // matchcnt + acc + cnt + wlcnt

    k0_geom<<<(AA + 255) / 256, 256, 0, stream>>>(xs_, ys_, st_, geom);

    dim3 grid1((AA + 255) / 256, BB);
    k1a_fg<<<grid1, 256, 0, stream>>>(outputs, labels, geom, alist, cnt, acc);

    dim3 grid1b(CAP / 256, BB);
    k1b_cls<<<grid1b, 256, 0, stream>>>(outputs, labels, geom, alist, cnt, blist, glist, misc, clsterm);

    dim3 grid2(GG, BB);
    k2_assign<<<grid2, 256, 0, stream>>>(labels, alist, cnt, blist, glist, clsterm, matchcnt, wl, wlcnt);

    k4_loss<<<CAPW / 256, 256, 0, stream>>>(outputs, origin, labels, xs_, ys_, st_,
                                            blist, glist, misc, clsterm, matchcnt, wl, wlcnt, acc);

    k5_final<<<1, 64, 0, stream>>>(acc, out);
}

// Round 5
// 248.115 us; speedup vs baseline: 2.5902x; 1.0790x over previous
//
#include <hip/hip_runtime.h>
#include <cfloat>

#define BB 32
#define AA 8400
#define GG 40
#define NC 80
#define NO 85
#define CAP 2048    // >= geometric bound ~27 anchors/gt * 40 gts = 1080
#define CAPW 13312  // >= 1280 gts * dk_max 10 = 12800

typedef unsigned long long ull;
#define U64MAX 0xFFFFFFFFFFFFFFFFull

// ---------- deterministic helpers: explicit _rn ops (no FMA contraction) so every
// call site produces bitwise-identical values ----------

__device__ inline bool dev_in(float gx, float gy, float xc, float yc, float r)
{
    float dl = __fsub_rn(xc, __fsub_rn(gx, r));
    float dr = __fsub_rn(__fadd_rn(gx, r), xc);
    float dt = __fsub_rn(yc, __fsub_rn(gy, r));
    float db = __fsub_rn(__fadd_rn(gy, r), yc);
    return fminf(fminf(dl, dr), fminf(dt, db)) > 0.0f;
}

__device__ inline float2 cost_iou(float gx, float gy, float gw, float gh,
                                  float px, float py, float pw, float ph,
                                  float xc, float yc, float r,
                                  float ct, float fg)
{
    bool in = dev_in(gx, gy, xc, yc, r);
    float gw2 = __fmul_rn(gw, 0.5f), gh2 = __fmul_rn(gh, 0.5f);
    float pw2 = __fmul_rn(pw, 0.5f), ph2 = __fmul_rn(ph, 0.5f);
    float tlx = fmaxf(__fsub_rn(gx, gw2), __fsub_rn(px, pw2));
    float tly = fmaxf(__fsub_rn(gy, gh2), __fsub_rn(py, ph2));
    float brx = fminf(__fadd_rn(gx, gw2), __fadd_rn(px, pw2));
    float bry = fminf(__fadd_rn(gy, gh2), __fadd_rn(py, ph2));
    float en = (tlx < brx && tly < bry) ? 1.0f : 0.0f;
    float ai = __fmul_rn(__fmul_rn(__fsub_rn(brx, tlx), __fsub_rn(bry, tly)), en);
    float ag = __fmul_rn(gw, gh);
    float ap = __fmul_rn(pw, ph);
    float iou = ai / __fsub_rn(__fadd_rn(ag, ap), ai);
    iou = (fg != 0.0f) ? iou : 0.0f;
    float icost = -__logf(__fadd_rn(iou, 1e-8f));
    float cost = __fadd_rn(__fadd_rn(ct, __fmul_rn(3.0f, icost)), in ? 0.0f : 1000000.0f);
    cost = (fg != 0.0f) ? cost : 1000000000.0f;
    return make_float2(cost, iou);
}

__device__ inline float wave_sum(float v)
{
#pragma unroll
    for (int o = 32; o > 0; o >>= 1) v += __shfl_down(v, o, 64);
    return v;
}

__device__ inline ull wave_min_u64(ull v)
{
#pragma unroll
    for (int o = 1; o < 64; o <<= 1) {
        ull w = (ull)__shfl_xor((long long)v, o, 64);
        v = w < v ? w : v;
    }
    return v;
}

__device__ inline float wave_max_f(float v)
{
#pragma unroll
    for (int o = 1; o < 64; o <<= 1) v = fmaxf(v, __shfl_xor(v, o, 64));
    return v;
}

// ---------- K1a: all anchors — geom (b==0), fg flag + compact list + obj-BCE base ----------
__global__ __launch_bounds__(256) void k1a_fg(
    const float* __restrict__ outputs, const float* __restrict__ labels,
    const float* __restrict__ xs_, const float* __restrict__ ys_, const float* __restrict__ st_,
    float4* __restrict__ geom,
    int* __restrict__ alist, int* __restrict__ cnt,
    float* __restrict__ acc)
{
    int b = blockIdx.y;
    int a = blockIdx.x * 256 + threadIdx.x;
    __shared__ float lgt[GG * 5];
    for (int i = threadIdx.x; i < GG * 5; i += 256) lgt[i] = labels[b * GG * 5 + i];
    __syncthreads();

    float sp = 0.0f;
    if (a < AA) {
        size_t idx = (size_t)b * AA + a;
        float obj = outputs[idx * NO + 4];
        sp = fmaxf(obj, 0.0f) + __logf(1.0f + __expf(-fabsf(obj)));  // BCE(obj, t=0)
        float stv = st_[a];
        float xc = __fmul_rn(__fadd_rn(xs_[a], 0.5f), stv);
        float yc = __fmul_rn(__fadd_rn(ys_[a], 0.5f), stv);
        float r  = __fmul_rn(1.5f, stv);
        if (b == 0) geom[a] = make_float4(xc, yc, r, stv);
        bool fg = false;
        for (int g = 0; g < GG && !fg; g++)
            fg = dev_in(lgt[g * 5 + 1], lgt[g * 5 + 2], xc, yc, r);
        if (fg) {
            int i = atomicAdd(&cnt[b], 1);
            if (i < CAP) alist[b * CAP + i] = a;
        }
    }
    sp = wave_sum(sp);
    __shared__ float red[4];
    if ((threadIdx.x & 63) == 0) red[threadIdx.x >> 6] = sp;
    __syncthreads();
    if (threadIdx.x == 0) atomicAdd(&acc[2], red[0] + red[1] + red[2] + red[3]);
}

// ---------- K1b: fg anchors — wave-staged coalesced row reads, class terms ----------
__global__ __launch_bounds__(256) void k1b_cls(
    const float* __restrict__ outputs, const float* __restrict__ labels,
    const float4* __restrict__ geom,
    const int* __restrict__ alist, const int* __restrict__ cnt,
    float4* __restrict__ blist, float4* __restrict__ glist,
    float2* __restrict__ misc, float* __restrict__ clsterm)
{
    int b = blockIdx.y;
    int i0 = blockIdx.x * 64;
    int n = cnt[b]; n = n > CAP ? CAP : n;
    if (i0 >= n) return;                      // uniform over block — safe before barriers

    __shared__ float rows[64 * NO];           // 21.8 KB, stride 85 (2-way conflicts only)
    __shared__ float lgt[GG * 5];
    __shared__ int   arow[64];
    __shared__ float2 red2[4][64];

    int tid = threadIdx.x;
    int w = tid >> 6, ln = tid & 63;
    for (int t = tid; t < GG * 5; t += 256) lgt[t] = labels[b * GG * 5 + t];

    // stage: each wave loads 16 rows, 85 dwords coalesced
    for (int rr = 0; rr < 16; rr++) {
        int row = i0 + w * 16 + rr;
        if (row < n) {
            int a = alist[b * CAP + row];
            const float* src = outputs + ((size_t)b * AA + a) * NO;
            int rl = w * 16 + rr;
            rows[rl * NO + ln] = src[ln];
            if (ln < NO - 64) rows[rl * NO + 64 + ln] = src[64 + ln];
            if (ln == 0) arow[rl] = a;
        }
    }
    __syncthreads();

    int il = ln;
    int i = i0 + il;
    bool valid = i < n;
    const float* R = rows + il * NO;
    float obj = R[4];

    float s1 = 0.0f, s2 = 0.0f;
    if (valid) {
        int c0 = w * 20;
#pragma unroll 4
        for (int j = 0; j < 20; j++) {
            float x = R[5 + c0 + j];
            float m = __fmul_rn(x, obj);
            float p = __fsqrt_rn(m);
            s1 += __logf(__fsub_rn(1.0f, p));                         // log1p(-p)
            s2 += fmaxf(x, 0.0f) + __logf(1.0f + __expf(-fabsf(x)));  // softplus base
        }
    }
    red2[w][il] = make_float2(s1, s2);
    __syncthreads();

    if (!valid) return;
    float s1t = red2[0][il].x + red2[1][il].x + red2[2][il].x + red2[3][il].x;
    float s2t = red2[0][il].y + red2[1][il].y + red2[2][il].y + red2[3][il].y;
    float nsl = -s1t;

    if (w == 0) {
        blist[b * CAP + i] = make_float4(R[0], R[1], R[2], R[3]);
        glist[b * CAP + i] = geom[arow[il]];
        misc[b * CAP + i]  = make_float2(s2t, obj);
    }
#pragma unroll
    for (int gi = 0; gi < 10; gi++) {
        int g = w * 10 + gi;
        int gc = (int)lgt[g * 5];
        float m = __fmul_rn(R[5 + gc], obj);
        float p = __fsqrt_rn(m);
        float term = __fsub_rn(__fmul_rn(0.5f, __logf(m)), __logf(__fsub_rn(1.0f, p)));
        clsterm[((size_t)b * GG + g) * CAP + i] = __fsub_rn(nsl, term);   // coalesced in i
    }
}

// ---------- K2: one wave per (b,g) — u64-key top-10 + iou top-10, register only ----------
__global__ __launch_bounds__(64) void k2_assign(
    const float* __restrict__ labels,
    const int* __restrict__ alist, const int* __restrict__ cnt,
    const float4* __restrict__ blist, const float4* __restrict__ glist,
    const float* __restrict__ clsterm,
    int* __restrict__ matchcnt, int2* __restrict__ wl, int* __restrict__ wlcnt)
{
    int g = blockIdx.x, b = blockIdx.y;
    int ln = threadIdx.x;
    const float* L = labels + (b * GG + g) * 5;
    float gx = L[1], gy = L[2], gw = L[3], gh = L[4];
    int n = cnt[b]; n = n > CAP ? CAP : n;

    const float*  ctp = clsterm + ((size_t)b * GG + g) * CAP;
    const float4* bp  = blist + b * CAP;
    const float4* gp  = glist + b * CAP;
    const int*    ap  = alist + b * CAP;

    ull t[10]; float tv[10];
#pragma unroll
    for (int k = 0; k < 10; k++) { t[k] = U64MAX; tv[k] = 0.0f; }

    for (int i = ln; i < n; i += 64) {
        float4 pb = bp[i];
        float4 gm = gp[i];
        float2 ci = cost_iou(gx, gy, gw, gh, pb.x, pb.y, pb.z, pb.w,
                             gm.x, gm.y, gm.z, ctp[i], 1.0f);
        // monotone float->uint flip, then pack tie-break key (anchor-major)
        unsigned u = __float_as_uint(ci.x);
        u ^= (u & 0x80000000u) ? 0xFFFFFFFFu : 0x80000000u;
        ull key = ((ull)u << 32) | (unsigned)((ap[i] << 11) | i);
        if (key < t[9]) {
            int p = 0;
#pragma unroll
            for (int k = 0; k < 10; k++) p += (t[k] < key) ? 1 : 0;
#pragma unroll
            for (int k = 9; k >= 1; k--) t[k] = (k > p) ? t[k - 1] : t[k];
#pragma unroll
            for (int k = 0; k < 10; k++) if (k == p) t[k] = key;
        }
        float v = ci.y;
        if (v > tv[9]) {
            int p = 0;
#pragma unroll
            for (int k = 0; k < 10; k++) p += (tv[k] > v) ? 1 : 0;
#pragma unroll
            for (int k = 9; k >= 1; k--) tv[k] = (k > p) ? tv[k - 1] : tv[k];
#pragma unroll
            for (int k = 0; k < 10; k++) if (k == p) tv[k] = v;
        }
    }

    // 10 rounds of wave-min extraction (keys unique -> single owner pops)
    ull mykey = U64MAX;
#pragma unroll
    for (int r = 0; r < 10; r++) {
        ull m = wave_min_u64(t[0]);
        if (ln == r) mykey = m;
        bool own = (t[0] == m);
#pragma unroll
        for (int k = 0; k < 9; k++) t[k] = own ? t[k + 1] : t[k];
        t[9] = own ? U64MAX : t[9];
    }
    // 10 rounds of wave-max for iou sum (ties -> ballot picks one owner)
    float isum = 0.0f;
#pragma unroll
    for (int r = 0; r < 10; r++) {
        float mv = wave_max_f(tv[0]);
        isum += mv;
        ull bal = __ballot(tv[0] == mv);
        int first = (int)__ffsll((long long)bal) - 1;
        bool own = (ln == first);
#pragma unroll
        for (int k = 0; k < 9; k++) tv[k] = own ? tv[k + 1] : tv[k];
        tv[9] = own ? 0.0f : tv[9];
    }

    int dk = (int)isum;
    dk = dk < 1 ? 1 : (dk > 10 ? 10 : dk);
    if (ln < dk) {
        unsigned low = (unsigned)mykey;
        int a = (int)(low >> 11);
        int i2 = (int)(low & 2047);
        int idx = b * AA + a;
        if (atomicAdd(&matchcnt[idx], 1) == 0) {
            int wp = atomicAdd(wlcnt, 1);
            if (wp < CAPW) wl[wp] = make_int2(idx, (g << 16) | i2);
        }
    }
}

// ---------- K4: dense loss over matched worklist + last-block finalize ----------
__global__ __launch_bounds__(256) void k4_loss(
    const float* __restrict__ outputs, const float* __restrict__ origin,
    const float* __restrict__ labels,
    const float* __restrict__ xs_, const float* __restrict__ ys_, const float* __restrict__ st_,
    const float4* __restrict__ blist, const float4* __restrict__ glist,
    const float2* __restrict__ misc, const float* __restrict__ clsterm,
    const int* __restrict__ matchcnt,
    const int2* __restrict__ wl, const int* __restrict__ wlcnt,
    float* __restrict__ acc, int* __restrict__ fin, float* __restrict__ out)
{
    int t = blockIdx.x * 256 + threadIdx.x;
    int nw = *wlcnt; nw = nw > CAPW ? CAPW : nw;

    float t_fg = 0.0f, t_iou = 0.0f, t_obj = 0.0f, t_cls = 0.0f, t_l1 = 0.0f;
    if (t < nw) {
        int2 e = wl[t];
        int idx = e.x;
        int b = idx / AA;
        int a = idx - b * AA;
        int ci = e.y & 0xFFFF;
        int g1 = e.y >> 16;
        int mcnt = matchcnt[idx];

        float4 pb = blist[b * CAP + ci];
        float4 gm = glist[b * CAP + ci];
        float2 mo = misc[b * CAP + ci];   // (sbce, obj)
        const float* Lb = labels + b * GG * 5;

        int mg;
        if (mcnt == 1) {
            mg = g1;
        } else {
            mg = 0; float best = FLT_MAX;
            for (int g = 0; g < GG; g++) {
                float ct = clsterm[((size_t)b * GG + g) * CAP + ci];
                float2 r = cost_iou(Lb[g * 5 + 1], Lb[g * 5 + 2], Lb[g * 5 + 3], Lb[g * 5 + 4],
                                    pb.x, pb.y, pb.z, pb.w, gm.x, gm.y, gm.z, ct, 1.0f);
                if (r.x < best) { best = r.x; mg = g; }
            }
        }
        t_fg = 1.0f;
        t_obj = -mo.y;   // BCE(x,1)-BCE(x,0); base summed in K1a
        float gx = Lb[mg * 5 + 1], gy = Lb[mg * 5 + 2], gw = Lb[mg * 5 + 3], gh = Lb[mg * 5 + 4];
        int mcls = (int)Lb[mg * 5];
        float ctm = clsterm[((size_t)b * GG + mg) * CAP + ci];
        float2 r = cost_iou(gx, gy, gw, gh, pb.x, pb.y, pb.z, pb.w, gm.x, gm.y, gm.z, ctm, 1.0f);
        float pred_iou = r.y;
        float tlx = fmaxf(pb.x - pb.z * 0.5f, gx - gw * 0.5f);
        float tly = fmaxf(pb.y - pb.w * 0.5f, gy - gh * 0.5f);
        float brx = fminf(pb.x + pb.z * 0.5f, gx + gw * 0.5f);
        float bry = fminf(pb.y + pb.w * 0.5f, gy + gh * 0.5f);
        float en = (tlx < brx && tly < bry) ? 1.0f : 0.0f;
        float ai = (brx - tlx) * (bry - tly) * en;
        float iou = ai / (pb.z * pb.w + gw * gh - ai + 1e-16f);
        t_iou = 1.0f - iou * iou;
        const float* op = origin + (size_t)idx * 4;
        float stv = st_[a], xsv = xs_[a], ysv = ys_[a];
        t_l1 = fabsf(op[0] - (gx / stv - xsv)) + fabsf(op[1] - (gy / stv - ysv))
             + fabsf(op[2] - logf(gw / stv + 1e-8f)) + fabsf(op[3] - logf(gh / stv + 1e-8f));
        t_cls = mo.x - outputs[(size_t)idx * NO + 5 + mcls] * pred_iou;
    }

    t_fg = wave_sum(t_fg); t_iou = wave_sum(t_iou); t_obj = wave_sum(t_obj);
    t_cls = wave_sum(t_cls); t_l1 = wave_sum(t_l1);
    __shared__ float red[5][4];
    int wv = threadIdx.x >> 6, ln = threadIdx.x & 63;
    if (ln == 0) { red[0][wv] = t_fg; red[1][wv] = t_iou; red[2][wv] = t_obj; red[3][wv] = t_cls; red[4][wv] = t_l1; }
    __syncthreads();
    if (threadIdx.x == 0) {
        atomicAdd(&acc[0], red[0][0] + red[0][1] + red[0][2] + red[0][3]);
        atomicAdd(&acc[1], red[1][0] + red[1][1] + red[1][2] + red[1][3]);
        atomicAdd(&acc[2], red[2][0] + red[2][1] + red[2][2] + red[2][3]);
        atomicAdd(&acc[3], red[3][0] + red[3][1] + red[3][2] + red[3][3]);
        atomicAdd(&acc[4], red[4][0] + red[4][1] + red[4][2] + red[4][3]);
        __threadfence();
        int tkt = atomicAdd(fin, 1);
        if (tkt == (int)gridDim.x - 1) {
            float a0 = atomicAdd(&acc[0], 0.0f);
            float a1 = atomicAdd(&acc[1], 0.0f);
            float a2 = atomicAdd(&acc[2], 0.0f);
            float a3 = atomicAdd(&acc[3], 0.0f);
            float a4 = atomicAdd(&acc[4], 0.0f);
            float nfg = fmaxf(a0, 1.0f);
            float li = 5.0f * a1 / nfg;
            float lo = a2 / nfg;
            float lc = a3 / nfg;
            float ll = a4 / nfg;
            out[0] = li + lo + lc + ll;
            out[1] = li;
            out[2] = lo;
            out[3] = lc;
            out[4] = ll;
            out[5] = nfg / (float)(BB * GG);
        }
    }
}

// ---------- workspace layout (16B-aligned blocks) ----------
static constexpr size_t NBA       = (size_t)BB * AA;                 // 268800
static constexpr size_t OFF_ACC   = NBA * 4;                         // matchcnt first
static constexpr size_t OFF_CNT   = OFF_ACC + 32;                    // acc[8]
static constexpr size_t OFF_WLC   = OFF_CNT + 128;                   // cnt[32]
static constexpr size_t OFF_GEOM  = OFF_WLC + 32;                    // wlcnt + fin
static constexpr size_t OFF_ALIST = OFF_GEOM + (size_t)AA * 16;
static constexpr size_t OFF_BL    = OFF_ALIST + (size_t)BB * CAP * 4;
static constexpr size_t OFF_GL    = OFF_BL + (size_t)BB * CAP * 16;
static constexpr size_t OFF_MISC  = OFF_GL + (size_t)BB * CAP * 16;
static constexpr size_t OFF_CT    = OFF_MISC + (size_t)BB * CAP * 8;
static constexpr size_t OFF_WL    = OFF_CT + (size_t)BB * GG * CAP * 4;
// total = OFF_WL + CAPW*8 ≈ 15 MB

extern "C" void kernel_launch(void* const* d_in, const int* in_sizes, int n_in,
                              void* d_out, int out_size, void* d_ws, size_t ws_size,
                              hipStream_t stream)
{
    (void)in_sizes; (void)n_in; (void)out_size; (void)ws_size;
    const float* outputs = (const float*)d_in[0];
    const float* origin  = (const float*)d_in[1];
    const float* labels  = (const float*)d_in[2];
    const float* xs_     = (const float*)d_in[3];
    const float* ys_     = (const float*)d_in[4];
    const float* st_     = (const float*)d_in[5];
    float* out = (float*)d_out;
    char* ws = (char*)d_ws;

    int*    matchcnt = (int*)(ws);
    float*  acc      = (float*)(ws + OFF_ACC);
    int*    cnt      = (int*)(ws + OFF_CNT);
    int*    wlcnt    = (int*)(ws + OFF_WLC);
    int*    fin      = (int*)(ws + OFF_WLC + 4);
    float4* geom     = (float4*)(ws + OFF_GEOM);
    int*    alist    = (int*)(ws + OFF_ALIST);
    float4* blist    = (float4*)(ws + OFF_BL);
    float4* glist    = (float4*)(ws + OFF_GL);
    float2* misc     = (float2*)(ws + OFF_MISC);
    float*  clsterm  = (float*)(ws + OFF_CT);
    int2*   wl       = (int2*)(ws + OFF_WL);

    hipMemsetAsync(ws, 0, OFF_GEOM, stream);   // matchcnt + acc + cnt + wlcnt + fin

    dim3 grid1((AA + 255) / 256, BB);
    k1a_fg<<<grid1, 256, 0, stream>>>(outputs, labels, xs_, ys_, st_, geom, alist, cnt, acc);

    dim3 grid1b(CAP / 64, BB);
    k1b_cls<<<grid1b, 256, 0, stream>>>(outputs, labels, geom, alist, cnt, blist, glist, misc, clsterm);

    dim3 grid2(GG, BB);
    k2_assign<<<grid2, 64, 0, stream>>>(labels, alist, cnt, blist, glist, clsterm, matchcnt, wl, wlcnt);

    k4_loss<<<CAPW / 256, 256, 0, stream>>>(outputs, origin, labels, xs_, ys_, st_,
                                            blist, glist, misc, clsterm, matchcnt, wl, wlcnt,
                                            acc, fin, out);
}